// Round 1
// baseline (10.477 us; speedup 1.0000x reference)
//
#include <hip/hip_runtime.h>

// TemporalConvSNNEncoder — exact-semantics shortcut.
//
// The reference applies lif_multistep SPIKE_DEPTH=2 times. The second
// application receives binary {0,1} input; with v <- (v+x)/2 starting at 0,
// v < 1 strictly for all time (v = 1 - 2^-k after k consecutive ones, exactly
// representable in fp32), so s = heaviside(v-1) == 0 everywhere.
// => final x == 0, spike_rate == 0, actor_feat[b] == proj_b for all b.
//
// Output layout (fp32, concatenated flat in return order):
//   [0,           B*128) : actor_feat[b][o] = proj_b[o]
//   [B*128, B*128 + B  ) : spike_rate[b]    = 0.0f

__global__ void TemporalConvSNNEncoder_write_const(const float* __restrict__ proj_b,
                                                   float* __restrict__ out,
                                                   int B) {
    const int nfeat = B * 128;
    const int total = nfeat + B;
    int i = blockIdx.x * blockDim.x + threadIdx.x;
    const int stride = gridDim.x * blockDim.x;
    for (; i < total; i += stride) {
        out[i] = (i < nfeat) ? proj_b[i & 127] : 0.0f;
    }
}

extern "C" void kernel_launch(void* const* d_in, const int* in_sizes, int n_in,
                              void* d_out, int out_size, void* d_ws, size_t ws_size,
                              hipStream_t stream) {
    // Input order per setup_inputs():
    // 0 hist_feat, 1 hist_valid_mask, 2 conv1_w, 3 conv1_b, 4 conv2_w,
    // 5 conv2_b, 6 ln_g, 7 ln_b, 8 proj_w, 9 proj_b
    const float* proj_b = (const float*)d_in[9];
    float* out = (float*)d_out;

    const int B = out_size / 129;   // out = B*128 actor_feat + B spike_rate

    const int block = 256;
    int total = out_size;
    int grid = (total + block - 1) / block;
    if (grid > 2048) grid = 2048;   // grid-stride the rest

    TemporalConvSNNEncoder_write_const<<<grid, block, 0, stream>>>(proj_b, out, B);
}

// Round 2
// 10.140 us; speedup vs baseline: 1.0332x; 1.0332x over previous
//
#include <hip/hip_runtime.h>

// TemporalConvSNNEncoder — exact-semantics shortcut, vectorized.
//
// Math (round 0 analysis, verified absmax=0): the second LIF layer receives
// binary {0,1} input; v <- (v+x)/2 from v0=0 gives v = 1 - 2^-k < 1 always
// (exact in fp32), so it never spikes. Final x == 0 =>
//   actor_feat[b][:] = proj_b, spike_rate[b] = 0.
//
// Output layout (fp32): [0, B*128) actor_feat; [B*128, B*129) spike_rate.
//
// This round: one float4 store per thread, exact-fit grid, no stride loop.
// B*128 % 4 == 0 and 128 % 4 == 0, so float4 i in the feat region maps to
// proj_b4[i & 31] (512 B table, L1-resident).

__global__ __launch_bounds__(256) void
TemporalConvSNNEncoder_write_const4(const float4* __restrict__ proj_b4,
                                    float4* __restrict__ out4,
                                    int nfeat4, int total4) {
    int i = blockIdx.x * blockDim.x + threadIdx.x;
    if (i >= total4) return;
    float4 v;
    if (i < nfeat4) {
        v = proj_b4[i & 31];          // 128 floats = 32 float4s, broadcast
    } else {
        v = make_float4(0.f, 0.f, 0.f, 0.f);
    }
    out4[i] = v;
}

extern "C" void kernel_launch(void* const* d_in, const int* in_sizes, int n_in,
                              void* d_out, int out_size, void* d_ws, size_t ws_size,
                              hipStream_t stream) {
    // Inputs: 0 hist_feat, 1 hist_valid_mask, 2 conv1_w, 3 conv1_b,
    //         4 conv2_w, 5 conv2_b, 6 ln_g, 7 ln_b, 8 proj_w, 9 proj_b
    const float4* proj_b4 = (const float4*)d_in[9];
    float4* out4 = (float4*)d_out;

    const int B = out_size / 129;
    const int nfeat4 = B * 32;            // B*128 floats / 4
    const int total4 = out_size / 4;      // B*129 / 4 (B=16384 -> divisible)

    const int block = 256;
    const int grid = (total4 + block - 1) / block;   // 2064 exact

    TemporalConvSNNEncoder_write_const4<<<grid, block, 0, stream>>>(
        proj_b4, out4, nfeat4, total4);
}